// Round 3
// baseline (493.270 us; speedup 1.0000x reference)
//
#include <hip/hip_runtime.h>
#include <hip/hip_bf16.h>

// CalcSpixelFeats R3. R2 post-mortem: atomicAdd(float) on generic pointers is
// CAS-expanded (flat fp-atomic unsafe) -> LDS pipe + VALU saturated at ~1
// lane-op/cy -> 365us invariant to occupancy. Fix:
//  - __hip_atomic_fetch_add(relaxed, workgroup) on __shared__ -> native ds_add_f32
//  - channel-in-lane accumulate: each ds_add has 32 consecutive addresses per
//    pixel (<=2-way bank aliasing, free) instead of 64 random banks
//  - invalid neighbors -> dummy acc row with w=0 (branch-free)
// Structure: per-block LDS acc [K+1][33]; tiles of 128 pixels staged in LDS
// (feats [128][33], (bin,w) pairs [128][9] as uint2); partials to d_ws; then
// reduce+normalize+transpose kernel (unchanged from R2).

#define CCH 32          // channels, fixed by problem
#define TPB 256
#define TILE 128        // pixels per tile
#define AS 33           // acc row stride (C + wsum), +1 -> bank spread
#define FS 33           // feats row stride
#define KMAX 256        // K = nw*nh = 256 for this problem

__device__ __forceinline__ void lds_fadd(float* p, float v) {
    (void)__hip_atomic_fetch_add(p, v, __ATOMIC_RELAXED,
                                 __HIP_MEMORY_SCOPE_WORKGROUP);
}

__global__ __launch_bounds__(TPB) void spx_accum_kernel(
    const float* __restrict__ pf,      // [B][C][P]
    const float* __restrict__ assoc,   // [B][9][P]
    const int*   __restrict__ idxmap,  // [B][P]
    const int*   __restrict__ nw_p,
    const int*   __restrict__ nh_p,
    float* __restrict__ part_f,        // [B*G][K][C]
    float* __restrict__ part_w,        // [B*G][K]
    int P, int K, int G, int ntiles)
{
    __shared__ float acc[(KMAX + 1) * AS];   // 33.9 KB (row K = dummy)
    __shared__ float feat[TILE * FS];        // 16.9 KB
    __shared__ uint2 bw[TILE * 9];           // 9.2 KB: {bin_row_offset, w bits}

    const int b   = blockIdx.x / G;
    const int g   = blockIdx.x % G;
    const int tid = threadIdx.x;
    const int nw  = nw_p[0];
    const int nh  = nh_p[0];

    for (int i = tid; i < (KMAX + 1) * AS; i += TPB) acc[i] = 0.0f;
    __syncthreads();

    const float* pf_b = pf     + (size_t)b * CCH * P;
    const float* as_b = assoc  + (size_t)b * 9 * P;
    const int*   ix_b = idxmap + (size_t)b * P;

    const int pl = tid & (TILE - 1);   // pixel lane within tile
    const int hh = tid >> 7;           // half: 0 or 1 (wave-uniform)
    const int c  = tid & 31;           // channel lane (phase B)
    const int q  = tid >> 5;           // pixel group 0..7 (phase B)

    for (int tile = g; tile < ntiles; tile += G) {
        const int p0 = tile * TILE;
        const int p  = p0 + pl;
        const bool pin = (p < P);

        // ---- Phase A: stage tile into LDS (coalesced global loads) ----
        // features: 16 channels per thread
#pragma unroll
        for (int cc = 0; cc < 16; ++cc) {
            const int ch = hh * 16 + cc;
            feat[pl * FS + ch] = pin ? pf_b[(size_t)ch * P + p] : 0.0f;
        }
        // bins + weights: split 9 planes across the two halves by parity
        const int idx = pin ? ix_b[p] : 0;
        const int iy  = idx / nw;
        const int ixx = idx - iy * nw;
#pragma unroll
        for (int j = 0; j < 9; ++j) {
            if ((j & 1) == hh) {
                const int dy = j / 3 - 1;
                const int dx = j % 3 - 1;
                const int ty = iy + dy;
                const int tx = ixx + dx;
                const bool valid =
                    (tx >= 0) & (tx < nw) & (ty >= 0) & (ty < nh) & pin;
                const float wj  = (pin ? as_b[(size_t)j * P + p] : 0.0f);
                const float wv  = valid ? wj : 0.0f;
                const int   off = valid ? (ty * nw + tx) * AS : K * AS;
                bw[pl * 9 + j] = make_uint2((unsigned)off, __float_as_uint(wv));
                lds_fadd(&acc[off + CCH], wv);   // wsum (few ops, cheap)
            }
        }
        __syncthreads();

        // ---- Phase B: channel-in-lane accumulate (conflict-free ds_add) ----
        for (int pp = q; pp < TILE; pp += 8) {
            const float f = feat[pp * FS + c];
#pragma unroll
            for (int j = 0; j < 9; ++j) {
                const uint2 e  = bw[pp * 9 + j];
                const float wj = __uint_as_float(e.y);
                lds_fadd(&acc[e.x + c], wj * f);
            }
        }
        __syncthreads();
    }

    // ---- Flush partials, coalesced ----
    float* pfo = part_f + (size_t)blockIdx.x * K * CCH;
    for (int i = tid; i < K * CCH; i += TPB) {
        const int t  = i >> 5;
        const int cc = i & 31;
        pfo[i] = acc[t * AS + cc];
    }
    float* pwo = part_w + (size_t)blockIdx.x * K;
    for (int i = tid; i < K; i += TPB) pwo[i] = acc[i * AS + CCH];
}

// One block per (b, t): 256 threads = 8 g-lanes x 32 channels.
__global__ __launch_bounds__(256) void spx_finalize_kernel(
    const float* __restrict__ part_f,  // [B*G][K][C]
    const float* __restrict__ part_w,  // [B*G][K]
    float* __restrict__ out,           // [B][C][K]
    int K, int G)
{
    const int b   = blockIdx.x / K;
    const int t   = blockIdx.x % K;
    const int tid = threadIdx.x;
    const int c   = tid & 31;
    const int g0  = tid >> 5;          // 0..7

    float fs = 0.0f, ws = 0.0f;
    for (int g = g0; g < G; g += 8) {
        const size_t row = (size_t)(b * G + g) * K + t;
        fs += part_f[row * CCH + c];
        ws += part_w[row];
    }

    __shared__ float redf[8][AS];
    redf[g0][c] = fs;
    if (c == 0) redf[g0][CCH] = ws;
    __syncthreads();

    if (tid < CCH) {
        float F = 0.0f, W = 0.0f;
#pragma unroll
        for (int r = 0; r < 8; ++r) {
            F += redf[r][tid];
            W += redf[r][CCH];
        }
        const float res = (W > 1e-16f) ? (F / W) : 0.0f;
        out[((size_t)b * CCH + tid) * K + t] = res;
    }
}

extern "C" void kernel_launch(void* const* d_in, const int* in_sizes, int n_in,
                              void* d_out, int out_size, void* d_ws, size_t ws_size,
                              hipStream_t stream) {
    const float* pf     = (const float*)d_in[0];
    const float* assoc  = (const float*)d_in[1];
    const int*   idxmap = (const int*)d_in[2];
    const int*   nw_p   = (const int*)d_in[3];
    const int*   nh_p   = (const int*)d_in[4];
    float* out = (float*)d_out;

    const int BP = in_sizes[2];          // B*P = 262144
    const int B  = 4;                    // fixed by reference setup
    const int P  = BP / B;               // 65536
    const int K  = out_size / (B * CCH); // 256 (== KMAX)

    int G = 128;                         // partial blocks per batch
    while (G > 8 &&
           (size_t)B * G * K * (CCH + 1) * sizeof(float) > ws_size) {
        G >>= 1;
    }
    const int ntiles = (P + TILE - 1) / TILE;

    float* part_f = (float*)d_ws;                       // [B*G][K][C]
    float* part_w = part_f + (size_t)B * G * K * CCH;   // [B*G][K]

    spx_accum_kernel<<<B * G, TPB, 0, stream>>>(
        pf, assoc, idxmap, nw_p, nh_p, part_f, part_w, P, K, G, ntiles);

    spx_finalize_kernel<<<B * K, 256, 0, stream>>>(
        part_f, part_w, out, K, G);
}